// Round 10
// baseline (556.212 us; speedup 1.0000x reference)
//
#include <hip/hip_runtime.h>
#include <hip/hip_bf16.h>
#include <math.h>

#define NB 4096      // tokens
#define ND 1024      // model dim
#define NH 4096      // hidden dim
#define NE 8         // experts
#define NKK 2        // top-k
#define NROWS (NB*NKK)   // 8192 (token,slot) rows
#define MAXT2 40         // 256-row tiles: 32 full + up to 8 partial

typedef __attribute__((ext_vector_type(8))) short short8;
typedef __attribute__((ext_vector_type(4))) float f32x4;

__device__ __forceinline__ void gload_lds16(const void* g, void* l) {
    __builtin_amdgcn_global_load_lds(
        (const __attribute__((address_space(1))) unsigned int*)g,
        (__attribute__((address_space(3))) unsigned int*)l, 16, 0, 0);
}

__device__ __forceinline__ unsigned short f2bf(float f) {
    __hip_bfloat16 h = __float2bfloat16(f);
    return *reinterpret_cast<unsigned short*>(&h);
}

// exact-gelu via A&S 7.1.26 erf approx (|erf err| < 1.5e-7), hw exp/rcp
__device__ __forceinline__ float fast_gelu(float x) {
    float xs  = x * 0.70710678118654752f;
    float axs = fabsf(xs);
    float t   = __builtin_amdgcn_rcpf(1.0f + 0.3275911f * axs);
    float p   = t * (0.254829592f + t * (-0.284496736f + t * (1.421413741f +
                t * (-1.453152027f + t * 1.061405429f))));
    float e   = __expf(-xs * xs);
    float erf_abs = 1.0f - p * e;
    float erf = copysignf(erf_abs, x);
    return 0.5f * x * (1.0f + erf);
}

// ---------------- prep kernels ----------------

// in: [E][R][C] f32  ->  out: [E][C][R] bf16  (transpose + convert)
__global__ void k_transpose_cvt(const float* __restrict__ in, __hip_bfloat16* __restrict__ out,
                                int R, int C) {
    __shared__ float tile[64][68];
    const size_t ebase = (size_t)blockIdx.z * R * C;
    const int r0 = blockIdx.y * 64, c0 = blockIdx.x * 64;
    const int t = threadIdx.x;
    const int lr = t >> 4, lc4 = (t & 15) * 4;
    #pragma unroll
    for (int i = 0; i < 4; ++i) {
        int r = lr + i * 16;
        float4 v = *reinterpret_cast<const float4*>(&in[ebase + (size_t)(r0 + r) * C + (c0 + lc4)]);
        *reinterpret_cast<float4*>(&tile[r][lc4]) = v;
    }
    __syncthreads();
    const int q = t & 15, cw = t >> 4;
    #pragma unroll
    for (int i = 0; i < 4; ++i) {
        int cc = cw + i * 16;
        ushort4 v;
        v.x = f2bf(tile[q*4+0][cc]);
        v.y = f2bf(tile[q*4+1][cc]);
        v.z = f2bf(tile[q*4+2][cc]);
        v.w = f2bf(tile[q*4+3][cc]);
        *reinterpret_cast<ushort4*>(&out[ebase + (size_t)(c0 + cc) * R + (r0 + q*4)]) = v;
    }
}

// ---------------- routing ----------------

__global__ void k_route_count(const int* __restrict__ idx, int* cnt) {
    int b = blockIdx.x * 256 + threadIdx.x;
    if (b < NB) {
        atomicAdd(&cnt[idx[2*b]], 1);
        atomicAdd(&cnt[idx[2*b+1]], 1);
    }
}

// prefix offsets + expert-pure 256-row tile list
__global__ void k_route_scan(const int* __restrict__ cnt, int* offs, int* cursor,
                             int* tile_e, int* tile_row, int* ntiles) {
    if (threadIdx.x == 0) {
        int s = 0, t = 0;
        for (int e = 0; e < NE; ++e) {
            offs[e] = s; cursor[e] = s;
            for (int r = 0; r < cnt[e]; r += 256) {
                tile_e[t] = e; tile_row[t] = s + r; ++t;
            }
            s += cnt[e];
        }
        offs[NE] = s;
        *ntiles = t;
    }
}

__global__ void k_route_fill(const int* __restrict__ idx, const float* __restrict__ hw,
                             int* cursor, int* tok, float* gw) {
    int b = blockIdx.x * 256 + threadIdx.x;
    if (b < NB) {
        #pragma unroll
        for (int k = 0; k < NKK; ++k) {
            int e = idx[2*b + k];
            int p = atomicAdd(&cursor[e], 1);
            tok[p] = b;
            gw[p]  = hw[2*b + k];
        }
    }
}

// gather + f32->bf16: Ag[row] = bf16(x[tok[row]])   (one block per row)
__global__ void k_gather_cvt(const float* __restrict__ x, const int* __restrict__ tok,
                             __hip_bfloat16* __restrict__ Ag) {
    const int row = blockIdx.x;
    const float4 v = reinterpret_cast<const float4*>(x + (size_t)tok[row] * ND)[threadIdx.x];
    ushort4 u; u.x = f2bf(v.x); u.y = f2bf(v.y); u.z = f2bf(v.z); u.w = f2bf(v.w);
    reinterpret_cast<ushort4*>(Ag + (size_t)row * ND)[threadIdx.x] = u;
}

// ---- 8-phase grouped GEMM: BM=BN=256, BK=64, 512thr/8 waves, 128KB dbuf ----
// STAGE 1: h = gelu(Ag @ w1t^T + b1)   K=1024, nt 0..15
// STAGE 2: out += gw*(h @ w2t^T + b2)  K=4096 splitK=4, nt 0..3
// Both: grid 640, KT=16, 1 block/CU.
//
// Per K-tile: 4 phases (ks, nhalf). Sub-stages S1={A.k0,B.k0} S2={A.k1,B.k1},
// 4 gload_lds instr each, issued at ph1/ph2 for tile t+1 into buf^1.
// vmcnt ledger (per wave, steady): entering ph1 {S1(t),S2(t)}=8 -> vmcnt(4)
// drains S1(t); entering ph3 {S2(t),S1(t+1),S2(t+1)}=12 -> vmcnt(8) drains
// S2(t). Last tile: ph3 vmcnt(0). Every vmcnt precedes a barrier before the
// dependent ds_reads (cross-wave publication). Raw s_barrier only (no
// implicit vmcnt(0) drain). LDS sub-tiles [ks][256 rows][32k] with rotation
// swizzle slot c=(kchunk+(row>>1))&3 -> 2-way banks (free).

template<int STAGE>
__global__ __launch_bounds__(512, 2) void moe_gemm8(
    const __hip_bfloat16* __restrict__ Asrc,   // Ag (st1) or h (st2)
    const __hip_bfloat16* __restrict__ Bt,     // [E][N][K] bf16
    const float* __restrict__ bias,            // [E][N]
    __hip_bfloat16* __restrict__ Hout,
    float* __restrict__ Out,
    const int* __restrict__ offs,
    const int* __restrict__ tok,
    const float* __restrict__ gw,
    const int* __restrict__ tile_e,
    const int* __restrict__ tile_row,
    const int* __restrict__ ntiles)
{
    constexpr int N    = (STAGE == 1) ? NH : ND;
    constexpr int KROW = (STAGE == 1) ? ND : NH;
    constexpr int KT   = 16;

    extern __shared__ char lds[];              // 131072 = 2 x (A 32K + B 32K)

    const int bid = blockIdx.x;
    const int wgid = (bid & 7) * 80 + (bid >> 3);
    const int tile = wgid % MAXT2;
    const int rest = wgid / MAXT2;             // st1: nt; st2: nt + 4*ksp
    if (tile >= *ntiles) return;

    int nt, kbase;
    if (STAGE == 1) { nt = rest;     kbase = 0; }
    else            { nt = rest & 3; kbase = (rest >> 2) * (NH / 4); }

    const int e = tile_e[tile];
    const int rowbase = tile_row[tile];
    const int end = offs[e + 1];

    const int tid = threadIdx.x;
    const int w = tid >> 6, l = tid & 63;
    const int l15 = l & 15, l4 = l >> 4;
    const int wm = (w >> 2) * 128;             // 0 / 128
    const int wn = (w & 3) * 64;               // 0..192

    // staging: thread covers rows srow (rr=0) and srow+128 (rr=1), chunk j
    const int srow = tid >> 2;
    const int j = ((tid & 3) - ((tid >> 3) & 3)) & 3;   // inverse rotation
    int ar0 = rowbase + srow;       if (ar0 > end - 1) ar0 = end - 1;
    int ar1 = rowbase + 128 + srow; if (ar1 > end - 1) ar1 = end - 1;
    const __hip_bfloat16* ap0 = Asrc + (size_t)ar0 * KROW + kbase + j * 8;
    const __hip_bfloat16* ap1 = Asrc + (size_t)ar1 * KROW + kbase + j * 8;
    const __hip_bfloat16* bp0 = Bt + ((size_t)e * N + nt * 256 + srow) * KROW + kbase + j * 8;
    const __hip_bfloat16* bp1 = Bt + ((size_t)e * N + nt * 256 + 128 + srow) * KROW + kbase + j * 8;

    // issue one half-operand pair: 2 gload_lds (op: 0=A, 1=B)
    auto STAGE_H = [&](int buf, int op, int ks, int kt) {
        char* d = lds + buf * 65536 + op * 32768 + ks * 16384 + tid * 16;
        const __hip_bfloat16* s0 = (op == 0 ? ap0 : bp0) + kt * 64 + ks * 32;
        const __hip_bfloat16* s1 = (op == 0 ? ap1 : bp1) + kt * 64 + ks * 32;
        gload_lds16(s0, d);
        gload_lds16(s1, d + 8192);
    };

    // ds_read byte offsets (rotation-swizzled)
    int aoff[8][2], boff[4][2];
    #pragma unroll
    for (int m = 0; m < 8; ++m) {
        int row = wm + m * 16 + l15;
        #pragma unroll
        for (int ks = 0; ks < 2; ++ks)
            aoff[m][ks] = ks * 16384 + row * 64 + (((l4 + (row >> 1)) & 3) * 16);
    }
    #pragma unroll
    for (int n = 0; n < 4; ++n) {
        int row = wn + n * 16 + l15;
        #pragma unroll
        for (int ks = 0; ks < 2; ++ks)
            boff[n][ks] = 32768 + ks * 16384 + row * 64 + (((l4 + (row >> 1)) & 3) * 16);
    }

    f32x4 acc[8][4];
    #pragma unroll
    for (int m = 0; m < 8; ++m)
        #pragma unroll
        for (int n = 0; n < 4; ++n) acc[m][n] = (f32x4){0.f, 0.f, 0.f, 0.f};

    // prologue: tile 0 into buf 0 (order: S1 = A.k0,B.k0 then S2 = A.k1,B.k1)
    STAGE_H(0, 0, 0, 0); STAGE_H(0, 1, 0, 0);
    STAGE_H(0, 0, 1, 0); STAGE_H(0, 1, 1, 0);

    #pragma unroll 1
    for (int t = 0; t < KT; ++t) {
        const int buf = t & 1;
        const char* sb = lds + buf * 65536;
        const bool notlast = (t + 1 < KT);
        short8 af[8], b0, b1;

        // ---------- ph1: ks=0, N-frags 0,1 ----------
        asm volatile("s_waitcnt vmcnt(4)" ::: "memory");   // S1(t) drained
        __builtin_amdgcn_sched_barrier(0);
        __builtin_amdgcn_s_barrier();                       // publish S1(t)
        #pragma unroll
        for (int m = 0; m < 8; ++m) af[m] = *(const short8*)(sb + aoff[m][0]);
        b0 = *(const short8*)(sb + boff[0][0]);
        b1 = *(const short8*)(sb + boff[1][0]);
        if (notlast) { STAGE_H(buf ^ 1, 0, 0, t + 1); STAGE_H(buf ^ 1, 1, 0, t + 1); }
        __builtin_amdgcn_s_barrier();
        asm volatile("s_waitcnt lgkmcnt(0)" ::: "memory");
        __builtin_amdgcn_sched_barrier(0);
        __builtin_amdgcn_s_setprio(1);
        #pragma unroll
        for (int m = 0; m < 8; ++m) {
            acc[m][0] = __builtin_amdgcn_mfma_f32_16x16x32_bf16(af[m], b0, acc[m][0], 0, 0, 0);
            acc[m][1] = __builtin_amdgcn_mfma_f32_16x16x32_bf16(af[m], b1, acc[m][1], 0, 0, 0);
        }
        __builtin_amdgcn_s_setprio(0);

        // ---------- ph2: ks=0, N-frags 2,3 ----------
        b0 = *(const short8*)(sb + boff[2][0]);
        b1 = *(const short8*)(sb + boff[3][0]);
        if (notlast) { STAGE_H(buf ^ 1, 0, 1, t + 1); STAGE_H(buf ^ 1, 1, 1, t + 1); }
        __builtin_amdgcn_s_barrier();
        asm volatile("s_waitcnt lgkmcnt(0)" ::: "memory");
        __builtin_amdgcn_sched_barrier(0);
        __builtin_amdgcn_s_setprio(1);
        #pragma unroll
        for (int m = 0; m < 8; ++m) {
            acc[m][2] = __builtin_amdgcn_mfma_f32_16x16x32_bf16(af[m], b0, acc[m][2], 0, 0, 0);
            acc[m][3] = __builtin_amdgcn_mfma_f32_16x16x32_bf16(af[m], b1, acc[m][3], 0, 0, 0);
        }
        __builtin_amdgcn_s_setprio(0);

        // ---------- ph3: ks=1, N-frags 0,1 ----------
        if (notlast) asm volatile("s_waitcnt vmcnt(8)" ::: "memory");  // S2(t) drained
        else         asm volatile("s_waitcnt vmcnt(0)" ::: "memory");
        __builtin_amdgcn_sched_barrier(0);
        __builtin_amdgcn_s_barrier();                       // publish S2(t)
        #pragma unroll
        for (int m = 0; m < 8; ++m) af[m] = *(const short8*)(sb + aoff[m][1]);
        b0 = *(const short8*)(sb + boff[0][1]);
        b1 = *(const short8*)(sb + boff[1][1]);
        __builtin_amdgcn_s_barrier();
        asm volatile("s_waitcnt lgkmcnt(0)" ::: "memory");
        __builtin_amdgcn_sched_barrier(0);
        __builtin_amdgcn_s_setprio(1);
        #pragma unroll
        for (int m = 0; m < 8; ++m) {
            acc[m][0] = __builtin_amdgcn_mfma_f32_16x16x32_bf16(af[m], b0, acc[m][0], 0, 0, 0);
            acc[m][1] = __builtin_amdgcn_mfma_f32_16x16x32_bf16(af[m], b1, acc[m][1], 0, 0, 0);
        }
        __builtin_amdgcn_s_setprio(0);

        // ---------- ph4: ks=1, N-frags 2,3 ----------
        b0 = *(const short8*)(sb + boff[2][1]);
        b1 = *(const short8*)(sb + boff[3][1]);
        __builtin_amdgcn_s_barrier();
        asm volatile("s_waitcnt lgkmcnt(0)" ::: "memory");
        __builtin_amdgcn_sched_barrier(0);
        __builtin_amdgcn_s_setprio(1);
        #pragma unroll
        for (int m = 0; m < 8; ++m) {
            acc[m][2] = __builtin_amdgcn_mfma_f32_16x16x32_bf16(af[m], b0, acc[m][2], 0, 0, 0);
            acc[m][3] = __builtin_amdgcn_mfma_f32_16x16x32_bf16(af[m], b1, acc[m][3], 0, 0, 0);
        }
        __builtin_amdgcn_s_setprio(0);
    }

    // epilogue --- C/D frag layout: col = l&15, row = (l>>4)*4 + j  [m89]
    const int ncol0 = nt * 256 + wn;
    #pragma unroll
    for (int m = 0; m < 8; ++m) {
        #pragma unroll
        for (int n = 0; n < 4; ++n) {
            const int gn = ncol0 + n * 16 + l15;
            const float bv = bias[e * N + gn];
            #pragma unroll
            for (int jj = 0; jj < 4; ++jj) {
                const int re = rowbase + wm + m * 16 + l4 * 4 + jj;
                if (re < end) {
                    float v = acc[m][n][jj];
                    if (STAGE == 1) {
                        v += bv;
                        Hout[(size_t)re * NH + gn] = __float2bfloat16(fast_gelu(v));
                    } else {
                        if (kbase == 0) v += bv;
                        atomicAdd(&Out[(size_t)tok[re] * ND + gn], gw[re] * v);
                    }
                }
            }
        }
    }
}

// ---------------- launch ----------------

extern "C" void kernel_launch(void* const* d_in, const int* in_sizes, int n_in,
                              void* d_out, int out_size, void* d_ws, size_t ws_size,
                              hipStream_t stream) {
    const float* x   = (const float*)d_in[0];
    const int*   idx = (const int*)d_in[1];
    const float* hw  = (const float*)d_in[2];
    const float* w1  = (const float*)d_in[3];
    const float* b1  = (const float*)d_in[4];
    const float* w2  = (const float*)d_in[5];
    const float* b2  = (const float*)d_in[6];
    float* out = (float*)d_out;

    char* ws = (char*)d_ws;
    size_t off = 0;
    __hip_bfloat16* Ag  = (__hip_bfloat16*)(ws + off); off += (size_t)NROWS * ND * 2;
    __hip_bfloat16* w1t = (__hip_bfloat16*)(ws + off); off += (size_t)NE * ND * NH * 2;
    __hip_bfloat16* w2t = (__hip_bfloat16*)(ws + off); off += (size_t)NE * NH * ND * 2;
    __hip_bfloat16* h   = (__hip_bfloat16*)(ws + off); off += (size_t)NROWS * NH * 2;
    int*   tok     = (int*)(ws + off);   off += NROWS * 4;
    float* gwb     = (float*)(ws + off); off += NROWS * 4;
    int*   cnt     = (int*)(ws + off);   off += 16 * 4;
    int*   offs    = (int*)(ws + off);   off += 16 * 4;
    int*   cursor  = (int*)(ws + off);   off += 16 * 4;
    int*   tile_e  = (int*)(ws + off);   off += MAXT2 * 4;
    int*   tile_row= (int*)(ws + off);   off += MAXT2 * 4;
    int*   ntiles  = (int*)(ws + off);   off += 16 * 4;
    (void)ws_size; (void)in_sizes; (void)n_in; (void)out_size;

    hipFuncSetAttribute((const void*)moe_gemm8<1>,
                        hipFuncAttributeMaxDynamicSharedMemorySize, 131072);
    hipFuncSetAttribute((const void*)moe_gemm8<2>,
                        hipFuncAttributeMaxDynamicSharedMemorySize, 131072);

    hipMemsetAsync(d_out, 0, (size_t)NB * ND * sizeof(float), stream);
    hipMemsetAsync(cnt, 0, 16 * 4, stream);

    k_route_count<<<dim3((NB + 255) / 256), 256, 0, stream>>>(idx, cnt);
    k_route_scan<<<1, 64, 0, stream>>>(cnt, offs, cursor, tile_e, tile_row, ntiles);
    k_route_fill<<<dim3((NB + 255) / 256), 256, 0, stream>>>(idx, hw, cursor, tok, gwb);
    k_gather_cvt<<<dim3(NROWS), 256, 0, stream>>>(x, tok, Ag);

    // LLC-aware interleave: each GEMM consumes weights converted just before it
    k_transpose_cvt<<<dim3(NH / 64, ND / 64, NE), 256, 0, stream>>>(w1, w1t, ND, NH);
    moe_gemm8<1><<<dim3(640), 512, 131072, stream>>>(
        Ag, w1t, b1, h, nullptr, offs, tok, gwb, tile_e, tile_row, ntiles);

    k_transpose_cvt<<<dim3(ND / 64, NH / 64, NE), 256, 0, stream>>>(w2, w2t, NH, ND);
    moe_gemm8<2><<<dim3(640), 512, 131072, stream>>>(
        h, w2t, b2, nullptr, out, offs, tok, gwb, tile_e, tile_row, ntiles);
}

// Round 11
// 427.953 us; speedup vs baseline: 1.2997x; 1.2997x over previous
//
#include <hip/hip_runtime.h>
#include <hip/hip_bf16.h>
#include <math.h>

#define NB 4096      // tokens
#define ND 1024      // model dim
#define NH 4096      // hidden dim
#define NE 8         // experts
#define NKK 2        // top-k
#define NROWS (NB*NKK)   // 8192 (token,slot) rows
#define MAXT 72          // max 128-row tiles (64 full + up to 8 partial)

typedef __attribute__((ext_vector_type(8))) short short8;
typedef __attribute__((ext_vector_type(4))) float f32x4;

__device__ __forceinline__ void gload_lds16(const void* g, void* l) {
    __builtin_amdgcn_global_load_lds(
        (const __attribute__((address_space(1))) unsigned int*)g,
        (__attribute__((address_space(3))) unsigned int*)l, 16, 0, 0);
}

__device__ __forceinline__ unsigned short f2bf(float f) {
    __hip_bfloat16 h = __float2bfloat16(f);
    return *reinterpret_cast<unsigned short*>(&h);
}

// exact-gelu via A&S 7.1.26 erf approx (|erf err| < 1.5e-7), hw exp/rcp
__device__ __forceinline__ float fast_gelu(float x) {
    float xs  = x * 0.70710678118654752f;
    float axs = fabsf(xs);
    float t   = __builtin_amdgcn_rcpf(1.0f + 0.3275911f * axs);
    float p   = t * (0.254829592f + t * (-0.284496736f + t * (1.421413741f +
                t * (-1.453152027f + t * 1.061405429f))));
    float e   = __expf(-xs * xs);
    float erf_abs = 1.0f - p * e;
    float erf = copysignf(erf_abs, x);
    return 0.5f * x * (1.0f + erf);
}

// ---------------- prep kernels ----------------

__global__ void k_cvt_x(const float* __restrict__ in, __hip_bfloat16* __restrict__ out, int n8) {
    int i = blockIdx.x * 256 + threadIdx.x;
    if (i >= n8) return;
    const float4* p = reinterpret_cast<const float4*>(in) + (size_t)i * 2;
    float4 a = p[0], b = p[1];
    ushort4 lo, hi;
    lo.x = f2bf(a.x); lo.y = f2bf(a.y); lo.z = f2bf(a.z); lo.w = f2bf(a.w);
    hi.x = f2bf(b.x); hi.y = f2bf(b.y); hi.z = f2bf(b.z); hi.w = f2bf(b.w);
    reinterpret_cast<ushort4*>(out)[(size_t)i*2]   = lo;
    reinterpret_cast<ushort4*>(out)[(size_t)i*2+1] = hi;
}

// in: [E][R][C] f32  ->  out: [E][C][R] bf16  (transpose + convert)
__global__ void k_transpose_cvt(const float* __restrict__ in, __hip_bfloat16* __restrict__ out,
                                int R, int C) {
    __shared__ float tile[64][68];
    const size_t ebase = (size_t)blockIdx.z * R * C;
    const int r0 = blockIdx.y * 64, c0 = blockIdx.x * 64;
    const int t = threadIdx.x;
    const int lr = t >> 4, lc4 = (t & 15) * 4;
    #pragma unroll
    for (int i = 0; i < 4; ++i) {
        int r = lr + i * 16;
        float4 v = *reinterpret_cast<const float4*>(&in[ebase + (size_t)(r0 + r) * C + (c0 + lc4)]);
        *reinterpret_cast<float4*>(&tile[r][lc4]) = v;
    }
    __syncthreads();
    const int q = t & 15, cw = t >> 4;
    #pragma unroll
    for (int i = 0; i < 4; ++i) {
        int cc = cw + i * 16;
        ushort4 v;
        v.x = f2bf(tile[q*4+0][cc]);
        v.y = f2bf(tile[q*4+1][cc]);
        v.z = f2bf(tile[q*4+2][cc]);
        v.w = f2bf(tile[q*4+3][cc]);
        *reinterpret_cast<ushort4*>(&out[ebase + (size_t)(c0 + cc) * R + (r0 + q*4)]) = v;
    }
}

// ---------------- routing ----------------

__global__ void k_route_count(const int* __restrict__ idx, int* cnt) {
    int b = blockIdx.x * 256 + threadIdx.x;
    if (b < NB) {
        atomicAdd(&cnt[idx[2*b]], 1);
        atomicAdd(&cnt[idx[2*b+1]], 1);
    }
}

// prefix offsets + expert-pure 128-row tile list
__global__ void k_route_scan(const int* __restrict__ cnt, int* offs, int* cursor,
                             int* tile_e, int* tile_row, int* ntiles) {
    if (threadIdx.x == 0) {
        int s = 0, t = 0;
        for (int e = 0; e < NE; ++e) {
            offs[e] = s; cursor[e] = s;
            for (int r = 0; r < cnt[e]; r += 128) {
                tile_e[t] = e; tile_row[t] = s + r; ++t;
            }
            s += cnt[e];
        }
        offs[NE] = s;
        *ntiles = t;
    }
}

__global__ void k_route_fill(const int* __restrict__ idx, const float* __restrict__ hw,
                             int* cursor, int* tok, float* gw) {
    int b = blockIdx.x * 256 + threadIdx.x;
    if (b < NB) {
        #pragma unroll
        for (int k = 0; k < NKK; ++k) {
            int e = idx[2*b + k];
            int p = atomicAdd(&cursor[e], 1);
            tok[p] = b;
            gw[p]  = hw[2*b + k];
        }
    }
}

// -------- grouped GEMM (r2-proven 2-barrier loop; 4 waves, BK=64) --------
// STAGE 1: h = gelu(Xg @ w1t^T + b1)  BM=128 BN=256, KT=16, grid 1152, 2 blk/CU
//          (wider N-tile halves per-XCD A-sweeps: FETCH down, MFMA:stage up)
// STAGE 2: out += gw*(h @ w2t^T + b2) BM=128 BN=128, KT=64, grid 576, 4 blk/CU
//          (exact r2 config, 141us proven)
// Mapping (r2): wgid = (bid&7)*CPX + bid>>3; tile fastest => ~9 consecutive
// blocks on one XCD share the (e,nt) weight panel.

template<int STAGE>
__global__ __launch_bounds__(256, (STAGE == 1) ? 2 : 4) void moe_gemm(
    const __hip_bfloat16* __restrict__ Asrc,   // xb (st1, tok-gathered) or h (st2)
    const __hip_bfloat16* __restrict__ Bt,     // [E][N][K] bf16
    const float* __restrict__ bias,            // [E][N]
    __hip_bfloat16* __restrict__ Hout,
    float* __restrict__ Out,
    const int* __restrict__ offs,
    const int* __restrict__ tok,
    const float* __restrict__ gw,
    const int* __restrict__ tile_e,
    const int* __restrict__ tile_row,
    const int* __restrict__ ntiles)
{
    constexpr int N    = (STAGE == 1) ? NH : ND;
    constexpr int KROW = (STAGE == 1) ? ND : NH;   // row stride of Asrc & Bt
    constexpr int KT   = (STAGE == 1) ? 16 : 64;   // K-tiles of 64 per block
    constexpr int BN   = (STAGE == 1) ? 256 : 128;
    constexpr int NF   = BN / 32;                  // n-frags per wave: 8 / 4
    constexpr int BLr  = BN / 32;                  // B staging rounds: 8 / 4
    constexpr int TOTAL = (N / BN) * MAXT;         // 1152 / 576
    constexpr int CPX  = TOTAL / 8;

    const int bid = blockIdx.x;
    const int wgid = (bid & 7) * CPX + (bid >> 3);
    const int tile = wgid % MAXT;
    const int nt   = wgid / MAXT;
    if (tile >= *ntiles) return;

    const int e = tile_e[tile];
    const int rowbase = tile_row[tile];
    const int end = offs[e + 1];

    __shared__ __align__(16) __hip_bfloat16 sA[128 * 64];
    __shared__ __align__(16) __hip_bfloat16 sB[BN * 64];

    const int tid = threadIdx.x;
    const int w = tid >> 6;
    const int l = tid & 63;

    // --- staging: pre-swizzled per-lane global sources, linear LDS dest ---
    const int srow = tid >> 3;                   // 0..31 (+ i*32)
    const int schunk = (tid & 7) ^ (srow & 7);   // XOR-swizzled source 16B chunk
    const __hip_bfloat16* aptr[4];
    #pragma unroll
    for (int i = 0; i < 4; ++i) {
        int r = srow + i * 32;
        int re = rowbase + r; if (re > end - 1) re = end - 1;
        if (STAGE == 1) aptr[i] = Asrc + (size_t)tok[re] * ND + schunk * 8;
        else            aptr[i] = Asrc + (size_t)re * NH + schunk * 8;
    }
    const __hip_bfloat16* bptr[BLr];
    #pragma unroll
    for (int i = 0; i < BLr; ++i)
        bptr[i] = Bt + ((size_t)e * N + (nt * BN + srow + i * 32)) * KROW + schunk * 8;

    __hip_bfloat16 *adst[4], *bdst[BLr];
    #pragma unroll
    for (int i = 0; i < 4; ++i)
        adst[i] = sA + (i * 256 + w * 64) * 8;   // wave-uniform, linear
    #pragma unroll
    for (int i = 0; i < BLr; ++i)
        bdst[i] = sB + (i * 256 + w * 64) * 8;

    const int wm = (w >> 1) * 64;
    const int wn = (w & 1) * (BN / 2);
    const int l15 = l & 15, l4 = l >> 4;

    f32x4 acc[4][NF];
    #pragma unroll
    for (int mi = 0; mi < 4; ++mi)
        #pragma unroll
        for (int ni = 0; ni < NF; ++ni) acc[mi][ni] = (f32x4){0.f, 0.f, 0.f, 0.f};

    // swizzled ds_read byte offsets
    int aoff[4][2], boff[NF][2];
    #pragma unroll
    for (int mi = 0; mi < 4; ++mi) {
        int row = wm + mi * 16 + l15;
        #pragma unroll
        for (int ks = 0; ks < 2; ++ks)
            aoff[mi][ks] = row * 128 + (((ks * 4 + l4) ^ (row & 7)) * 16);
    }
    #pragma unroll
    for (int ni = 0; ni < NF; ++ni) {
        int row = wn + ni * 16 + l15;
        #pragma unroll
        for (int ks = 0; ks < 2; ++ks)
            boff[ni][ks] = row * 128 + (((ks * 4 + l4) ^ (row & 7)) * 16);
    }

    const char* sAb = (const char*)sA;
    const char* sBb = (const char*)sB;

    #pragma unroll 1
    for (int kt = 0; kt < KT; ++kt) {
        #pragma unroll
        for (int i = 0; i < 4; ++i)
            gload_lds16(aptr[i] + kt * 64, adst[i]);
        #pragma unroll
        for (int i = 0; i < BLr; ++i)
            gload_lds16(bptr[i] + kt * 64, bdst[i]);
        __syncthreads();
        // process in ks-halves, B-frags in chunks of 4 (caps live registers)
        #pragma unroll
        for (int ks = 0; ks < 2; ++ks) {
            short8 af[4];
            #pragma unroll
            for (int mi = 0; mi < 4; ++mi)
                af[mi] = *(const short8*)(sAb + aoff[mi][ks]);
            #pragma unroll
            for (int nh = 0; nh < NF / 4; ++nh) {
                short8 bfr[4];
                #pragma unroll
                for (int nj = 0; nj < 4; ++nj)
                    bfr[nj] = *(const short8*)(sBb + boff[nh * 4 + nj][ks]);
                #pragma unroll
                for (int mi = 0; mi < 4; ++mi)
                    #pragma unroll
                    for (int nj = 0; nj < 4; ++nj)
                        acc[mi][nh * 4 + nj] = __builtin_amdgcn_mfma_f32_16x16x32_bf16(
                            af[mi], bfr[nj], acc[mi][nh * 4 + nj], 0, 0, 0);
            }
        }
        __syncthreads();
    }

    // --- epilogue --- C/D layout: col = lane&15, row = (lane>>4)*4 + j  [m89]
    const int ncol0 = nt * BN + wn;
    #pragma unroll
    for (int mi = 0; mi < 4; ++mi) {
        #pragma unroll
        for (int ni = 0; ni < NF; ++ni) {
            int gn = ncol0 + ni * 16 + l15;
            float bv = bias[e * N + gn];
            #pragma unroll
            for (int j = 0; j < 4; ++j) {
                int re = rowbase + wm + mi * 16 + l4 * 4 + j;
                if (re < end) {
                    float v = acc[mi][ni][j] + bv;
                    if (STAGE == 1) {
                        Hout[(size_t)re * NH + gn] = __float2bfloat16(fast_gelu(v));
                    } else {
                        atomicAdd(&Out[(size_t)tok[re] * ND + gn], gw[re] * v);
                    }
                }
            }
        }
    }
}

// ---------------- launch ----------------

extern "C" void kernel_launch(void* const* d_in, const int* in_sizes, int n_in,
                              void* d_out, int out_size, void* d_ws, size_t ws_size,
                              hipStream_t stream) {
    const float* x   = (const float*)d_in[0];
    const int*   idx = (const int*)d_in[1];
    const float* hw  = (const float*)d_in[2];
    const float* w1  = (const float*)d_in[3];
    const float* b1  = (const float*)d_in[4];
    const float* w2  = (const float*)d_in[5];
    const float* b2  = (const float*)d_in[6];
    float* out = (float*)d_out;

    char* ws = (char*)d_ws;
    size_t off = 0;
    __hip_bfloat16* xb  = (__hip_bfloat16*)(ws + off); off += (size_t)NB * ND * 2;
    __hip_bfloat16* w1t = (__hip_bfloat16*)(ws + off); off += (size_t)NE * ND * NH * 2;
    __hip_bfloat16* w2t = (__hip_bfloat16*)(ws + off); off += (size_t)NE * NH * ND * 2;
    __hip_bfloat16* h   = (__hip_bfloat16*)(ws + off); off += (size_t)NROWS * NH * 2;
    int*   tok     = (int*)(ws + off);   off += NROWS * 4;
    float* gwb     = (float*)(ws + off); off += NROWS * 4;
    int*   cnt     = (int*)(ws + off);   off += 16 * 4;
    int*   offs    = (int*)(ws + off);   off += 16 * 4;
    int*   cursor  = (int*)(ws + off);   off += 16 * 4;
    int*   tile_e  = (int*)(ws + off);   off += MAXT * 4;
    int*   tile_row= (int*)(ws + off);   off += MAXT * 4;
    int*   ntiles  = (int*)(ws + off);   off += 16 * 4;
    (void)ws_size; (void)in_sizes; (void)n_in; (void)out_size;

    hipMemsetAsync(d_out, 0, (size_t)NB * ND * sizeof(float), stream);
    hipMemsetAsync(cnt, 0, 16 * 4, stream);

    k_cvt_x<<<dim3((NB * ND / 8 + 255) / 256), 256, 0, stream>>>(x, xb, NB * ND / 8);
    k_transpose_cvt<<<dim3(NH / 64, ND / 64, NE), 256, 0, stream>>>(w1, w1t, ND, NH);
    k_transpose_cvt<<<dim3(ND / 64, NH / 64, NE), 256, 0, stream>>>(w2, w2t, NH, ND);
    k_route_count<<<dim3((NB + 255) / 256), 256, 0, stream>>>(idx, cnt);
    k_route_scan<<<1, 64, 0, stream>>>(cnt, offs, cursor, tile_e, tile_row, ntiles);
    k_route_fill<<<dim3((NB + 255) / 256), 256, 0, stream>>>(idx, hw, cursor, tok, gwb);

    moe_gemm<1><<<dim3((NH / 256) * MAXT), 256, 0, stream>>>(
        xb, w1t, b1, h, nullptr, offs, tok, gwb, tile_e, tile_row, ntiles);
    moe_gemm<2><<<dim3((ND / 128) * MAXT), 256, 0, stream>>>(
        h, w2t, b2, nullptr, out, offs, tok, gwb, tile_e, tile_row, ntiles);
}